// Round 1
// baseline (208.886 us; speedup 1.0000x reference)
//
#include <hip/hip_runtime.h>
#include <stdint.h>

#define H_DIM 4096
#define I_DIM 11008
#define NGH   (H_DIM/128)   // 32 groups along H (gate/up)
#define NGI   (I_DIM/128)   // 86 groups along I (down)

typedef __attribute__((ext_vector_type(8))) short short8;
typedef __attribute__((ext_vector_type(4))) float f32x4;
typedef __attribute__((ext_vector_type(4))) int   i32x4;

// f32 -> bf16 bits, round-to-nearest-even
static __device__ __forceinline__ short f2bf(float f) {
  uint32_t u = __builtin_bit_cast(uint32_t, f);
  u = (u + 0x7FFFu + ((u >> 16) & 1u)) >> 16;
  return (short)(uint16_t)u;
}

__global__ void xcvt_kernel(const float* __restrict__ x, short* __restrict__ xb) {
  int i = blockIdx.x * 256 + threadIdx.x;
  xb[i] = f2bf(x[i]);
}

// gate+up GEMM + SwiGLU fused.  Grid: I_DIM/16 blocks, 256 thr (4 waves).
// Each wave: 16 output cols (i), K-segment of 1024, M=64 via 4 MFMA m-chunks.
__global__ __launch_bounds__(256) void phase1_kernel(
    const short* __restrict__ xb,
    const int* __restrict__ gq, const float* __restrict__ gsc, const float* __restrict__ gze,
    const int* __restrict__ uq, const float* __restrict__ usc, const float* __restrict__ uze,
    short* __restrict__ hb)
{
  __shared__ float red[2][4][4][4][64];   // [proj][wave][mchunk][reg][lane] = 32 KB
  const int n0   = blockIdx.x * 16;
  const int w    = threadIdx.x >> 6;
  const int l    = threadIdx.x & 63;
  const int col  = l & 15;
  const int krow = l >> 4;
  const int i    = n0 + col;

  const int*   gqr = gq + (size_t)i * H_DIM;
  const int*   uqr = uq + (size_t)i * H_DIM;
  const float* gsr = gsc + (size_t)i * NGH;
  const float* gzr = gze + (size_t)i * NGH;
  const float* usr = usc + (size_t)i * NGH;
  const float* uzr = uze + (size_t)i * NGH;

  f32x4 accG[4], accU[4];
#pragma unroll
  for (int c = 0; c < 4; ++c)
#pragma unroll
    for (int r = 0; r < 4; ++r) { accG[c][r] = 0.f; accU[c][r] = 0.f; }

  const int g0 = w * 8;                    // 8 groups of 128 per wave (K=1024)
#pragma unroll 1
  for (int g = g0; g < g0 + 8; ++g) {
    const float sg = gsr[g], zg = gzr[g] * sg;   // w = q*s - z*s
    const float su = usr[g], zu = uzr[g] * su;
#pragma unroll
    for (int ks = 0; ks < 4; ++ks) {
      const int koff = g * 128 + ks * 32 + krow * 8;
      short8 a[4];
#pragma unroll
      for (int c = 0; c < 4; ++c)
        a[c] = *(const short8*)(xb + (size_t)(c * 16 + col) * H_DIM + koff);
      i32x4 q0 = *(const i32x4*)(gqr + koff);
      i32x4 q1 = *(const i32x4*)(gqr + koff + 4);
      i32x4 p0 = *(const i32x4*)(uqr + koff);
      i32x4 p1 = *(const i32x4*)(uqr + koff + 4);
      short8 bg, bu;
#pragma unroll
      for (int j = 0; j < 4; ++j) {
        bg[j]     = f2bf((float)q0[j] * sg - zg);
        bg[j + 4] = f2bf((float)q1[j] * sg - zg);
        bu[j]     = f2bf((float)p0[j] * su - zu);
        bu[j + 4] = f2bf((float)p1[j] * su - zu);
      }
#pragma unroll
      for (int c = 0; c < 4; ++c) {
        accG[c] = __builtin_amdgcn_mfma_f32_16x16x32_bf16(a[c], bg, accG[c], 0, 0, 0);
        accU[c] = __builtin_amdgcn_mfma_f32_16x16x32_bf16(a[c], bu, accU[c], 0, 0, 0);
      }
    }
  }

#pragma unroll
  for (int c = 0; c < 4; ++c)
#pragma unroll
    for (int r = 0; r < 4; ++r) {
      red[0][w][c][r][l] = accG[c][r];
      red[1][w][c][r][l] = accU[c][r];
    }
  __syncthreads();

  {
    const int c  = threadIdx.x >> 6;
    const int ll = threadIdx.x & 63;
#pragma unroll
    for (int r = 0; r < 4; ++r) {
      float gsum = red[0][0][c][r][ll] + red[0][1][c][r][ll]
                 + red[0][2][c][r][ll] + red[0][3][c][r][ll];
      float usum = red[1][0][c][r][ll] + red[1][1][c][r][ll]
                 + red[1][2][c][r][ll] + red[1][3][c][r][ll];
      float hv = gsum / (1.f + __expf(-gsum)) * usum;   // silu(g)*u
      const int m  = c * 16 + (ll >> 4) * 4 + r;        // C/D: row=(l>>4)*4+r
      const int ii = n0 + (ll & 15);                    //      col=l&15
      hb[(size_t)m * I_DIM + ii] = f2bf(hv);
    }
  }
}

// down GEMM.  Grid: H_DIM/16 blocks, 512 thr (8 waves), K-split 1376 per wave.
__global__ __launch_bounds__(512) void phase2_kernel(
    const short* __restrict__ hb,
    const int* __restrict__ dq, const float* __restrict__ dsc, const float* __restrict__ dze,
    float* __restrict__ out)
{
  __shared__ float red[8][4][4][64];   // 32 KB
  const int n0   = blockIdx.x * 16;
  const int w    = threadIdx.x >> 6;   // 0..7
  const int l    = threadIdx.x & 63;
  const int col  = l & 15;
  const int krow = l >> 4;
  const int n    = n0 + col;

  const int*   dqr = dq + (size_t)n * I_DIM;
  const float* dsr = dsc + (size_t)n * NGI;
  const float* dzr = dze + (size_t)n * NGI;

  f32x4 acc[4];
#pragma unroll
  for (int c = 0; c < 4; ++c)
#pragma unroll
    for (int r = 0; r < 4; ++r) acc[c][r] = 0.f;

  const int kbeg = w * (I_DIM / 8);    // 1376, 43 K-steps of 32
  int gprev = -1;
  float sv = 0.f, zv = 0.f;
#pragma unroll 1
  for (int ks = 0; ks < 43; ++ks) {
    const int k0 = kbeg + ks * 32;
    const int g  = k0 >> 7;            // uniform across wave
    if (g != gprev) { sv = dsr[g]; zv = dzr[g] * sv; gprev = g; }
    const int koff = k0 + krow * 8;
    short8 a[4];
#pragma unroll
    for (int c = 0; c < 4; ++c)
      a[c] = *(const short8*)(hb + (size_t)(c * 16 + col) * I_DIM + koff);
    i32x4 q0 = *(const i32x4*)(dqr + koff);
    i32x4 q1 = *(const i32x4*)(dqr + koff + 4);
    short8 b;
#pragma unroll
    for (int j = 0; j < 4; ++j) {
      b[j]     = f2bf((float)q0[j] * sv - zv);
      b[j + 4] = f2bf((float)q1[j] * sv - zv);
    }
#pragma unroll
    for (int c = 0; c < 4; ++c)
      acc[c] = __builtin_amdgcn_mfma_f32_16x16x32_bf16(a[c], b, acc[c], 0, 0, 0);
  }

#pragma unroll
  for (int c = 0; c < 4; ++c)
#pragma unroll
    for (int r = 0; r < 4; ++r)
      red[w][c][r][l] = acc[c][r];
  __syncthreads();

  if (threadIdx.x < 256) {
    const int c  = threadIdx.x >> 6;
    const int ll = threadIdx.x & 63;
#pragma unroll
    for (int r = 0; r < 4; ++r) {
      float s = 0.f;
#pragma unroll
      for (int ww = 0; ww < 8; ++ww) s += red[ww][c][r][ll];
      const int m  = c * 16 + (ll >> 4) * 4 + r;
      const int nn = n0 + (ll & 15);
      out[(size_t)m * H_DIM + nn] = s;
    }
  }
}

extern "C" void kernel_launch(void* const* d_in, const int* in_sizes, int n_in,
                              void* d_out, int out_size, void* d_ws, size_t ws_size,
                              hipStream_t stream) {
  const float* x  = (const float*)d_in[0];
  const int*   gq = (const int*)d_in[1];
  const float* gs = (const float*)d_in[2];
  const float* gz = (const float*)d_in[3];
  const int*   uq = (const int*)d_in[4];
  const float* us = (const float*)d_in[5];
  const float* uz = (const float*)d_in[6];
  const int*   dq = (const int*)d_in[7];
  const float* ds = (const float*)d_in[8];
  const float* dz = (const float*)d_in[9];
  float* out = (float*)d_out;

  // ws layout: [0, 512KB) x_bf16 [64][4096];  [512KB, +1.376MB) h_bf16 [64][11008]
  short* xb = (short*)d_ws;
  short* hb = (short*)((char*)d_ws + (size_t)64 * H_DIM * 2);

  xcvt_kernel<<<(64 * H_DIM) / 256, 256, 0, stream>>>(x, xb);
  phase1_kernel<<<I_DIM / 16, 256, 0, stream>>>(xb, gq, gs, gz, uq, us, uz, hb);
  phase2_kernel<<<H_DIM / 16, 512, 0, stream>>>(hb, dq, ds, dz, out);
}

// Round 5
// 207.665 us; speedup vs baseline: 1.0059x; 1.0059x over previous
//
#include <hip/hip_runtime.h>
#include <hip/hip_bf16.h>
#include <stdint.h>

#define H_DIM 4096
#define I_DIM 11008
#define NGH   (H_DIM/128)   // 32 groups along H (gate/up)
#define NGI   (I_DIM/128)   // 86 groups along I (down)

typedef __attribute__((ext_vector_type(8))) short short8;
typedef __attribute__((ext_vector_type(4))) short s16x4;
typedef __attribute__((ext_vector_type(4))) float f32x4;
typedef __attribute__((ext_vector_type(4))) int   i32x4;

static __device__ __forceinline__ short f2bf(float f) {
  union { __hip_bfloat16 b; short s; } u;
  u.b = __float2bfloat16(f);
  return u.s;
}

__global__ void xcvt_kernel(const float* __restrict__ x, short* __restrict__ xb) {
  int i = (blockIdx.x * 256 + threadIdx.x) * 4;
  f32x4 v = *(const f32x4*)(x + i);
  s16x4 o;
  o[0] = f2bf(v[0]); o[1] = f2bf(v[1]); o[2] = f2bf(v[2]); o[3] = f2bf(v[3]);
  *(s16x4*)(xb + i) = o;
}

// gate+up GEMM + SwiGLU fused.  Grid: I_DIM/16 blocks, 512 thr (8 waves).
// Wave w: 16 output cols, K-segment of 512 (4 groups), M=64 via 4 MFMA chunks.
__global__ __launch_bounds__(512, 4) void phase1_kernel(
    const short* __restrict__ xb,
    const int* __restrict__ gq, const float* __restrict__ gsc, const float* __restrict__ gze,
    const int* __restrict__ uq, const float* __restrict__ usc, const float* __restrict__ uze,
    short* __restrict__ hb)
{
  __shared__ float red[8][4][4][64];   // 32 KB, reused for G then U
  const int n0   = blockIdx.x * 16;
  const int w    = threadIdx.x >> 6;
  const int l    = threadIdx.x & 63;
  const int col  = l & 15;
  const int krow = l >> 4;
  const int i    = n0 + col;

  const int*   gqr = gq + (size_t)i * H_DIM;
  const int*   uqr = uq + (size_t)i * H_DIM;
  const float* gsr = gsc + (size_t)i * NGH;
  const float* gzr = gze + (size_t)i * NGH;
  const float* usr = usc + (size_t)i * NGH;
  const float* uzr = uze + (size_t)i * NGH;

  f32x4 accG[4], accU[4];
#pragma unroll
  for (int c = 0; c < 4; ++c)
#pragma unroll
    for (int r = 0; r < 4; ++r) { accG[c][r] = 0.f; accU[c][r] = 0.f; }

  const int kw = w * 512;              // wave K base

  // 1-deep weight prefetch
  int pk = kw + krow * 8;
  i32x4 nq0 = *(const i32x4*)(gqr + pk);
  i32x4 nq1 = *(const i32x4*)(gqr + pk + 4);
  i32x4 np0 = *(const i32x4*)(uqr + pk);
  i32x4 np1 = *(const i32x4*)(uqr + pk + 4);

#pragma unroll 1
  for (int g = 0; g < 4; ++g) {
    const int gg = w * 4 + g;
    const float sg = gsr[gg], zg = gzr[gg] * sg;   // w = q*s - z*s
    const float su = usr[gg], zu = uzr[gg] * su;
#pragma unroll
    for (int ks = 0; ks < 4; ++ks) {
      i32x4 q0 = nq0, q1 = nq1, p0 = np0, p1 = np1;
      const int klocal = g * 128 + ks * 32;
      // prefetch next k-step (wraps to 0 on last iter; always in-bounds)
      {
        const int nk = kw + ((klocal + 32) & 511) + krow * 8;
        nq0 = *(const i32x4*)(gqr + nk);
        nq1 = *(const i32x4*)(gqr + nk + 4);
        np0 = *(const i32x4*)(uqr + nk);
        np1 = *(const i32x4*)(uqr + nk + 4);
      }
      const int koff = kw + klocal + krow * 8;
      short8 a[4];
#pragma unroll
      for (int c = 0; c < 4; ++c)
        a[c] = *(const short8*)(xb + (size_t)(c * 16 + col) * H_DIM + koff);
      short8 bg, bu;
#pragma unroll
      for (int j = 0; j < 4; ++j) {
        bg[j]     = f2bf((float)q0[j] * sg - zg);
        bg[j + 4] = f2bf((float)q1[j] * sg - zg);
        bu[j]     = f2bf((float)p0[j] * su - zu);
        bu[j + 4] = f2bf((float)p1[j] * su - zu);
      }
#pragma unroll
      for (int c = 0; c < 4; ++c) {
        accG[c] = __builtin_amdgcn_mfma_f32_16x16x32_bf16(a[c], bg, accG[c], 0, 0, 0);
        accU[c] = __builtin_amdgcn_mfma_f32_16x16x32_bf16(a[c], bu, accU[c], 0, 0, 0);
      }
    }
  }

  const int c2 = threadIdx.x >> 7;          // 0..3 m-chunk
  const int rh = (threadIdx.x >> 6) & 1;    // r half
  const int ll = threadIdx.x & 63;

  // reduce gate
#pragma unroll
  for (int c = 0; c < 4; ++c)
#pragma unroll
    for (int r = 0; r < 4; ++r)
      red[w][c][r][l] = accG[c][r];
  __syncthreads();
  float gsum[2];
#pragma unroll
  for (int rr = 0; rr < 2; ++rr) {
    const int r = rh * 2 + rr;
    float s = 0.f;
#pragma unroll
    for (int ww = 0; ww < 8; ++ww) s += red[ww][c2][r][ll];
    gsum[rr] = s;
  }
  __syncthreads();

  // reduce up + swiglu + store
#pragma unroll
  for (int c = 0; c < 4; ++c)
#pragma unroll
    for (int r = 0; r < 4; ++r)
      red[w][c][r][l] = accU[c][r];
  __syncthreads();
#pragma unroll
  for (int rr = 0; rr < 2; ++rr) {
    const int r = rh * 2 + rr;
    float us = 0.f;
#pragma unroll
    for (int ww = 0; ww < 8; ++ww) us += red[ww][c2][r][ll];
    const float gv = gsum[rr];
    const float hv = gv / (1.f + __expf(-gv)) * us;    // silu(g)*u
    const int m  = c2 * 16 + (ll >> 4) * 4 + r;        // C/D: row=(l>>4)*4+r
    const int ii = n0 + (ll & 15);                     //      col=l&15
    hb[(size_t)m * I_DIM + ii] = f2bf(hv);
  }
}

// down GEMM, split-K x4 across blocks.  Grid: (H_DIM/16)*4 blocks, 512 thr.
// Block (tile, split): 16 cols, K-range of 2752 (86 steps of 32) over 8 waves.
__global__ __launch_bounds__(512, 4) void phase2_kernel(
    const short* __restrict__ hb,
    const int* __restrict__ dq, const float* __restrict__ dsc, const float* __restrict__ dze,
    float* __restrict__ part)
{
  __shared__ float red[8][4][4][64];   // 32 KB
  const int tile  = blockIdx.x & 255;
  const int split = blockIdx.x >> 8;
  const int n0   = tile * 16;
  const int w    = threadIdx.x >> 6;   // 0..7
  const int l    = threadIdx.x & 63;
  const int col  = l & 15;
  const int krow = l >> 4;
  const int n    = n0 + col;

  const int*   dqr = dq + (size_t)n * I_DIM;
  const float* dsr = dsc + (size_t)n * NGI;
  const float* dzr = dze + (size_t)n * NGI;

  f32x4 acc[4];
#pragma unroll
  for (int c = 0; c < 4; ++c)
#pragma unroll
    for (int r = 0; r < 4; ++r) acc[c][r] = 0.f;

  // 86 steps over 8 waves: waves 0-5 take 11, waves 6-7 take 10
  const int cnt    = (w < 6) ? 11 : 10;
  const int sstart = (w < 6) ? w * 11 : 66 + (w - 6) * 10;
  const int kbase  = split * 2752 + sstart * 32;

  int gprev = -1;
  float sv = 0.f, zv = 0.f;

  int pk = kbase + krow * 8;
  i32x4 nq0 = *(const i32x4*)(dqr + pk);
  i32x4 nq1 = *(const i32x4*)(dqr + pk + 4);

#pragma unroll 1
  for (int s = 0; s < cnt; ++s) {
    i32x4 q0 = nq0, q1 = nq1;
    {
      const int ns = (s + 1 < cnt) ? (s + 1) : 0;   // wrap: harmless in-bounds load
      const int nk = kbase + ns * 32 + krow * 8;
      nq0 = *(const i32x4*)(dqr + nk);
      nq1 = *(const i32x4*)(dqr + nk + 4);
    }
    const int k0 = kbase + s * 32;
    const int g  = k0 >> 7;            // uniform across wave per step
    if (g != gprev) { sv = dsr[g]; zv = dzr[g] * sv; gprev = g; }
    short8 a[4];
#pragma unroll
    for (int c = 0; c < 4; ++c)
      a[c] = *(const short8*)(hb + (size_t)(c * 16 + col) * I_DIM + k0 + krow * 8);
    short8 b;
#pragma unroll
    for (int j = 0; j < 4; ++j) {
      b[j]     = f2bf((float)q0[j] * sv - zv);
      b[j + 4] = f2bf((float)q1[j] * sv - zv);
    }
#pragma unroll
    for (int c = 0; c < 4; ++c)
      acc[c] = __builtin_amdgcn_mfma_f32_16x16x32_bf16(a[c], b, acc[c], 0, 0, 0);
  }

#pragma unroll
  for (int c = 0; c < 4; ++c)
#pragma unroll
    for (int r = 0; r < 4; ++r)
      red[w][c][r][l] = acc[c][r];
  __syncthreads();

  {
    const int c2 = threadIdx.x >> 7;
    const int rh = (threadIdx.x >> 6) & 1;
    const int ll = threadIdx.x & 63;
    float* po = part + (size_t)split * (64 * H_DIM);
#pragma unroll
    for (int rr = 0; rr < 2; ++rr) {
      const int r = rh * 2 + rr;
      float s = 0.f;
#pragma unroll
      for (int ww = 0; ww < 8; ++ww) s += red[ww][c2][r][ll];
      const int m  = c2 * 16 + (ll >> 4) * 4 + r;
      const int nn = n0 + (ll & 15);
      po[(size_t)m * H_DIM + nn] = s;
    }
  }
}

__global__ void reduce4_kernel(const float* __restrict__ part, float* __restrict__ out) {
  const int idx = (blockIdx.x * 256 + threadIdx.x) * 4;
  const int S = 64 * H_DIM;
  f32x4 s0 = *(const f32x4*)(part + idx);
  f32x4 s1 = *(const f32x4*)(part + S + idx);
  f32x4 s2 = *(const f32x4*)(part + 2 * S + idx);
  f32x4 s3 = *(const f32x4*)(part + 3 * S + idx);
  f32x4 r = (s0 + s1) + (s2 + s3);
  *(f32x4*)(out + idx) = r;
}

extern "C" void kernel_launch(void* const* d_in, const int* in_sizes, int n_in,
                              void* d_out, int out_size, void* d_ws, size_t ws_size,
                              hipStream_t stream) {
  const float* x  = (const float*)d_in[0];
  const int*   gq = (const int*)d_in[1];
  const float* gs = (const float*)d_in[2];
  const float* gz = (const float*)d_in[3];
  const int*   uq = (const int*)d_in[4];
  const float* us = (const float*)d_in[5];
  const float* uz = (const float*)d_in[6];
  const int*   dq = (const int*)d_in[7];
  const float* ds = (const float*)d_in[8];
  const float* dz = (const float*)d_in[9];
  float* out = (float*)d_out;

  // ws: [0,512K) x_bf16 [64][4096]; [512K,+1.376M) h_bf16 [64][11008];
  //     then f32 partials [4][64][4096] (4 MB)
  short* xb = (short*)d_ws;
  short* hb = (short*)((char*)d_ws + (size_t)64 * H_DIM * 2);
  float* part = (float*)((char*)d_ws + (size_t)64 * H_DIM * 2 + (size_t)64 * I_DIM * 2);

  xcvt_kernel<<<(64 * H_DIM) / 1024, 256, 0, stream>>>(x, xb);
  phase1_kernel<<<I_DIM / 16, 512, 0, stream>>>(xb, gq, gs, gz, uq, us, uz, hb);
  phase2_kernel<<<(H_DIM / 16) * 4, 512, 0, stream>>>(hb, dq, ds, dz, part);
  reduce4_kernel<<<(64 * H_DIM) / 1024, 256, 0, stream>>>(part, out);
}